// Round 18
// baseline (298.342 us; speedup 1.0000x reference)
//
#include <hip/hip_runtime.h>

#define NA 384
#define NB 384
#define NBATCH 64
#define NEGV -1e20f
#define C 16           // steps per chunk
#define NCW 3          // compute waves; 128 rows each, 2 rows per lane
#define TOT_CH 28      // s = 1..448 covers 447 wavefront steps
#define WP 20          // wtile row pitch (floats); rows 16B-aligned
#define SP 33          // stage lane pitch (32 vals + 1 pad)
#define LOG2E 1.44269504088896340736f
#define LN2   0.69314718055994530942f
#define MUP (NB + 1)

typedef float f4 __attribute__((ext_vector_type(4)));

struct alignas(16) SharedT {
    float stage[2][NCW][64 * SP];    // 50.7 KB: [ring][wave][lane*SP + 2c+z]
    float wtile[3][NCW][128 * WP];   // 92.2 KB: consumer layout, swizzled
    float bound[NCW - 1][NB + 1];    // rows 128w, log2-domain (same protocol)
    int   progress[NCW - 1];
    int   computed[NCW];
    int   drained[NCW][2];
    int   wready[NCW];
};

// IO: skewed-coalesced load of one chunk's W band (128 rows x 16 cols).
// instr (i,h): rows 8i..8i+7 x 8 cols, ~9 cache lines each.
__device__ __forceinline__ void loadW32(const float* __restrict__ Wb, int bb,
                                        int kk, int l, float (&r)[32])
{
    const int rl = l >> 3, cc = l & 7;
#pragma unroll
    for (int i = 0; i < 16; ++i) {
        const int row = 8 * i + rl;
        const int cb = 16 * kk + cc - (row >> 1);
#pragma unroll
        for (int h = 0; h < 2; ++h) {
            int col = cb + 8 * h;
            col = col < 0 ? 0 : (col > NB - 1 ? NB - 1 : col);
            r[2 * i + h] = Wb[(size_t)(bb + row) * NB + col];
        }
    }
}

// IO: write to consumer layout wtile[row][c], XOR-swizzled 4-float groups,
// premultiplied by LOG2E.  value(row, c) = W[row][16k + c - row/2].
__device__ __forceinline__ void writeWt32(float* __restrict__ wt,
                                          const float (&r)[32], int l)
{
    const int rl = l >> 3, cc = l & 7;
#pragma unroll
    for (int i = 0; i < 16; ++i) {
        const int row = 8 * i + rl;
        const int sw4 = (row >> 4) & 3;
#pragma unroll
        for (int h = 0; h < 2; ++h) {
            const int c = cc + 8 * h;
            wt[row * WP + 4 * ((c >> 2) ^ sw4) + (c & 3)] = r[2 * i + h] * LOG2E;
        }
    }
}

// Compute lane L: rows 2L (wcA) and 2L+1 (wcB); de-swizzled f4 reads.
__device__ __forceinline__ void readW2(const float* __restrict__ wt, int L,
                                       float (&wcA)[16], float (&wcB)[16])
{
    const int sw = (L >> 3) & 3;
    const float* pA = wt + (2 * L) * WP;
    const float* pB = wt + (2 * L + 1) * WP;
#pragma unroll
    for (int cb = 0; cb < 4; ++cb) {
        const f4 a = *(const f4*)(pA + 4 * (cb ^ sw));
        const f4 b = *(const f4*)(pB + 4 * (cb ^ sw));
        wcA[4 * cb + 0] = a.x; wcA[4 * cb + 1] = a.y;
        wcA[4 * cb + 2] = a.z; wcA[4 * cb + 3] = a.w;
        wcB[4 * cb + 0] = b.x; wcB[4 * cb + 1] = b.y;
        wcB[4 * cb + 2] = b.z; wcB[4 * cb + 3] = b.w;
    }
}

// FULL: all lanes in j-range for all 16 steps (k in [4,23])
template<bool FULL>
__device__ __forceinline__ void chunk_body(int k, int w, int l,
        float (&wcA)[16], float (&wcB)[16],
        float& valA, float& valB, float& diagA, float& m2A, float& m2B,
        SharedT& sh)
{
    const int s0 = 1 + k * C;

    // stage ring slot free?
    if (k >= 2) {
        volatile int* dr = &sh.drained[w][k & 1];
        while (*dr < k - 2) __builtin_amdgcn_s_sleep(1);
        __builtin_amdgcn_sched_barrier(0);
        asm volatile("" ::: "memory");
    }
    // producer boundary ready? (bare spin: the latency-critical relay edge)
    if (w > 0 && s0 <= NB) {
        const int need = (s0 + C - 1 < NB) ? s0 + C - 1 : NB;
        volatile int* pr = &sh.progress[w - 1];
        while (*pr < need) { }
        __builtin_amdgcn_sched_barrier(0);
        asm volatile("" ::: "memory");
    }
    float bnd[C];
    if (w > 0) {
#pragma unroll
        for (int c = 0; c < C; ++c) {
            const int s = s0 + c;
            bnd[c] = sh.bound[w - 1][s <= NB ? s : NB];
        }
    }

    float nvAr[C] = {}, nvBr[C] = {};
    __builtin_amdgcn_s_setprio(1);
    // ---- 16 relay steps: 2 cells per lane per step ----
#pragma unroll
    for (int c = 0; c < C; ++c) {
        const int s = s0 + c;
        float upA = __int_as_float(__builtin_amdgcn_update_dpp(
            0, __float_as_int(valB), 0x138 /*WAVE_SHR1*/, 0xF, 0xF, false));
        if (l == 0) upA = (w > 0 && s <= NB) ? bnd[c] : NEGV;
        const int j = s - l;
        if (FULL || (j >= 1 && j <= NB)) {
            // cell A: row 2l+1 — up=upA, left=valA, diag=diagA
            const float mA  = fmaxf(upA, m2A);
            const float mwA = mA + wcA[c];
            const float a1 = exp2f(upA   - mA);
            const float a2 = exp2f(valA  - mA);
            const float a3 = exp2f(diagA - mA);
            const float nvA = mwA + __log2f((a1 + a2) + a3);
            // cell B: row 2l+2 — up=nvA, left=valB, diag=valA (pre-update)
            const float mB  = fmaxf(nvA, m2B);
            const float mwB = mB + wcB[c];
            const float b1 = exp2f(nvA  - mB);
            const float b2 = exp2f(valB - mB);
            const float b3 = exp2f(valA - mB);
            const float nvB = mwB + __log2f((b1 + b2) + b3);
            nvAr[c] = nvA; nvBr[c] = nvB;
            m2A = fmaxf(nvA, upA);     // next step: max(valA', diagA')
            m2B = fmaxf(nvB, nvA);     // next step: max(valB', valA')
            diagA = upA;
            valA  = nvA;
            valB  = nvB;
        }
    }

    // ---- relay edge first (prio 1): bound writes + progress ----
    if (w < NCW - 1) {
        if (l == 63) {
#pragma unroll
            for (int c = 0; c < C; ++c) {
                const int j63 = s0 + c - 63;
                if (j63 >= 1 && j63 <= NB) sh.bound[w][j63] = nvBr[c];
            }
        }
        asm volatile("s_waitcnt lgkmcnt(0)" ::: "memory");
        if (l == 63) {
            const int done = s0 + C - 1 - 63;
            if (done >= 1) *(volatile int*)&sh.progress[w] = done;
        }
    }
    __builtin_amdgcn_s_setprio(0);

    // ---- staging writes + computed publish ----
    float* st = &sh.stage[k & 1][w][0] + l * SP;
#pragma unroll
    for (int c = 0; c < C; ++c) {
        st[2 * c]     = nvAr[c];
        st[2 * c + 1] = nvBr[c];
    }
    asm volatile("s_waitcnt lgkmcnt(0)" ::: "memory");
    if (l == 63) *(volatile int*)&sh.computed[w] = k + 1;

    // next chunk's W (wready published 2 io-iterations ago -> instant)
    if (k + 1 < TOT_CH) {
        volatile int* wr = &sh.wready[w];
        while (*wr < k + 2) { }
        __builtin_amdgcn_sched_barrier(0);
        asm volatile("" ::: "memory");
        readW2(&sh.wtile[(k + 1) % 3][w][0], l, wcA, wcB);
    }
}

// ---------------- IO iteration: drain mu, feed W ----------------
template<bool FULL>
__device__ __forceinline__ void io_iter(int k, int cw, int l,
        const float* __restrict__ Wb, int bb, float* __restrict__ mub,
        float (&wreg)[32], SharedT& sh)
{
    volatile int* cp = &sh.computed[cw];
    while (*cp < k + 1) __builtin_amdgcn_s_sleep(8);
    __builtin_amdgcn_sched_barrier(0);
    asm volatile("" ::: "memory");

    // stage -> regs: lane t = (lr = t>>4, cc = t&15); q-th cell is
    // row r = lr + 4q, col j = 16k+1+cc - (r>>1).
    const float* st = &sh.stage[k & 1][cw][0];
    const int lr = l >> 4, cc = l & 15;
    float v[32];
#pragma unroll
    for (int q = 0; q < 32; ++q) {
        const int r = lr + 4 * q;
        v[q] = st[(r >> 1) * SP + 2 * cc + (r & 1)];
    }
    asm volatile("s_waitcnt lgkmcnt(0)" ::: "memory");
    if (l == 0) *(volatile int*)&sh.drained[cw][k & 1] = k;

    // W tile for chunk k+3 from a ~2-period-old register load
    if (k + 3 < TOT_CH) {
        writeWt32(&sh.wtile[(k + 3) % 3][cw][0], wreg, l);
        asm volatile("s_waitcnt lgkmcnt(0)" ::: "memory");
        if (l == 0) *(volatile int*)&sh.wready[cw] = k + 4;
        if (k + 5 < TOT_CH) loadW32(Wb, bb, k + 5, l, wreg);
    }

    // mu stores (fire-and-forget): 4 rows x 16 consecutive cols per instr
#pragma unroll
    for (int q = 0; q < 32; ++q) {
        const int r = lr + 4 * q;
        const int j = 16 * k + 1 + cc - (r >> 1);     // 1-based col
        if (FULL || ((unsigned)(j - 1) < (unsigned)NB))
            mub[(size_t)(bb + r + 1) * MUP + j] = v[q] * LN2;
    }
}

__global__ __launch_bounds__(384, 1) void dtw_mu(const float* __restrict__ W,
                                                 float* __restrict__ mu)
{
    __shared__ SharedT sh;
    const int b = blockIdx.x, tid = threadIdx.x;
    const int w = tid >> 6, l = tid & 63;
    const float* Wb = W + (size_t)b * NA * NB;
    float* mub = mu + (size_t)b * MUP * MUP;

    mub[tid + 1] = NEGV;                          // row 0, cols 1..384
    mub[(size_t)(tid + 1) * MUP] = NEGV;          // col 0, rows 1..384
    if (tid == 0) mub[0] = 0.0f;
    if (tid < NCW - 1) sh.progress[tid] = 0;
    if (tid < NCW) { sh.computed[tid] = 0; sh.wready[tid] = 0; }
    if (tid < 2 * NCW) sh.drained[tid >> 1][tid & 1] = -1;
    __syncthreads();

    if (w < NCW) {
        // -------- compute wave: rows 128w+1 .. 128w+128, 2 rows/lane --------
        float valA = NEGV, valB = NEGV;
        float diagA = (w == 0 && l == 0) ? 0.0f : NEGV;
        float m2A = fmaxf(valA, diagA);
        float m2B = NEGV;
        float wcA[16], wcB[16];
        {
            volatile int* wr = &sh.wready[w];
            while (*wr < 1) { }
            __builtin_amdgcn_sched_barrier(0);
            asm volatile("" ::: "memory");
            readW2(&sh.wtile[0][w][0], l, wcA, wcB);
        }
        for (int k = 0; k < 4; ++k)
            chunk_body<false>(k, w, l, wcA, wcB, valA, valB, diagA, m2A, m2B, sh);
        for (int k = 4; k < 24; ++k)
            chunk_body<true >(k, w, l, wcA, wcB, valA, valB, diagA, m2A, m2B, sh);
        for (int k = 24; k < TOT_CH; ++k)
            chunk_body<false>(k, w, l, wcA, wcB, valA, valB, diagA, m2A, m2B, sh);
    } else {
        // -------- IO wave: W feed + mu drain for compute wave cw --------
        const int cw = w - NCW;
        const int bb = cw << 7;                   // band base row (0-based)
        float r0[32], rA[32], rB[32];
        loadW32(Wb, bb, 0, l, r0);
        writeWt32(&sh.wtile[0][cw][0], r0, l);
        loadW32(Wb, bb, 1, l, r0);
        writeWt32(&sh.wtile[1][cw][0], r0, l);
        loadW32(Wb, bb, 2, l, r0);
        writeWt32(&sh.wtile[2][cw][0], r0, l);
        loadW32(Wb, bb, 3, l, rA);
        loadW32(Wb, bb, 4, l, rB);
        asm volatile("s_waitcnt lgkmcnt(0)" ::: "memory");
        if (l == 0) *(volatile int*)&sh.wready[cw] = 3;

        for (int k = 0; k < 4; k += 2) {
            io_iter<false>(k,     cw, l, Wb, bb, mub, rA, sh);
            io_iter<false>(k + 1, cw, l, Wb, bb, mub, rB, sh);
        }
        for (int k = 4; k < 24; k += 2) {
            io_iter<true >(k,     cw, l, Wb, bb, mub, rA, sh);
            io_iter<true >(k + 1, cw, l, Wb, bb, mub, rB, sh);
        }
        for (int k = 24; k < TOT_CH; k += 2) {
            io_iter<false>(k,     cw, l, Wb, bb, mub, rA, sh);
            io_iter<false>(k + 1, cw, l, Wb, bb, mub, rB, sh);
        }
    }
}

// ---------------- pass 2: pi = exp(x + W - mu_ij) * mask ----------------
__global__ __launch_bounds__(256) void dtw_pi(const float* __restrict__ W,
        const float* __restrict__ mask, const float* __restrict__ mu,
        float* __restrict__ pi)
{
    const long long idx = ((long long)blockIdx.x * 256 + threadIdx.x) * 4;
    const int rr = (int)(idx / NB);
    const int jj = (int)(idx - (long long)rr * NB);
    const int b  = rr / NA;
    const int ii = rr - b * NA;
    const float* m0 = mu + (size_t)b * MUP * MUP + (size_t)ii * MUP + jj;
    const float* m1 = m0 + MUP;
    const float d0 = m0[0], d1 = m0[1], d2 = m0[2], d3 = m0[3], d4 = m0[4];
    const float L0 = m1[0], L1 = m1[1], L2 = m1[2], L3 = m1[3], L4 = m1[4];
    const f4 wv = *(const f4*)(W + idx);
    const f4 mk = *(const f4*)(mask + idx);

    const float t0 = wv.x - L1, t1 = wv.y - L2, t2 = wv.z - L3, t3 = wv.w - L4;
    f4 o0, o1, o2;
    o0.x = exp2f((d1 + t0) * LOG2E) * mk.x;
    o0.y = exp2f((L0 + t0) * LOG2E) * mk.x;
    o0.z = exp2f((d0 + t0) * LOG2E) * mk.x;
    o0.w = exp2f((d2 + t1) * LOG2E) * mk.y;
    o1.x = exp2f((L1 + t1) * LOG2E) * mk.y;
    o1.y = exp2f((d1 + t1) * LOG2E) * mk.y;
    o1.z = exp2f((d3 + t2) * LOG2E) * mk.z;
    o1.w = exp2f((L2 + t2) * LOG2E) * mk.z;
    o2.x = exp2f((d2 + t2) * LOG2E) * mk.z;
    o2.y = exp2f((d4 + t3) * LOG2E) * mk.w;
    o2.z = exp2f((L3 + t3) * LOG2E) * mk.w;
    o2.w = exp2f((d3 + t3) * LOG2E) * mk.w;

    f4* po = (f4*)(pi + idx * 3);
    po[0] = o0; po[1] = o1; po[2] = o2;
}

extern "C" void kernel_launch(void* const* d_in, const int* in_sizes, int n_in,
                              void* d_out, int out_size, void* d_ws, size_t ws_size,
                              hipStream_t stream) {
    const float* W    = (const float*)d_in[0];
    const float* mask = (const float*)d_in[1];
    float* mu = (float*)d_out;
    float* pi = mu + (size_t)NBATCH * MUP * MUP;

    hipLaunchKernelGGL(dtw_mu, dim3(NBATCH), dim3(384), 0, stream, W, mu);

    const int cells  = NBATCH * NA * NB;
    const int blocks = cells / (256 * 4);
    hipLaunchKernelGGL(dtw_pi, dim3(blocks), dim3(256), 0, stream,
                       W, mask, mu, pi);
}

// Round 19
// 144.652 us; speedup vs baseline: 2.0625x; 2.0625x over previous
//
#include <hip/hip_runtime.h>

#define NA 384
#define NB 384
#define NBATCH 64
#define NEGV -1e20f
#define C 16           // steps per chunk
#define NCW 6          // compute waves (rows 64w+1..64w+64)
#define TOT_CH 28      // chunks: s0 = 1 + 16k, k = 0..27
#define WPITCH 60      // wtile row pitch (floats)
#define SP 17          // stage row pitch (16 steps + 1 pad)
#define LOG2E 1.44269504088896340736f
#define LN2   0.69314718055994530942f
#define MUP (NB + 1)

typedef float f4 __attribute__((ext_vector_type(4)));

struct alignas(16) SharedT {
    float stage[3][NCW][64 * SP];      // mu' staging ring, 3-DEEP (78.3 KB)
    float wtile[3][NCW][16 * WPITCH];  // transposed W ring (69.1 KB)
    float bound[NCW - 1][NB + 1];      // boundary rows mu'[64w][1..384]
    int   progress[NCW - 1];
    int   computed[NCW];
    int   drained[NCW][3];             // per ring slot
    int   wready[NCW];
};

// Skewed-coalesced W load (8 cache lines/instr), two 8-col groups.
__device__ __forceinline__ void loadW16(const float* __restrict__ Wb, int rbase,
                                        int k, int l, float (&r)[16])
{
    const int rl = l >> 3, cc = l & 7;
#pragma unroll
    for (int h = 0; h < 2; ++h) {
        const int colb = 8 * (2 * k + h) + cc;
#pragma unroll
        for (int i = 0; i < 8; ++i) {
            const int row = 8 * i + rl;
            int col = colb - row;
            col = col < 0 ? 0 : (col > NB - 1 ? NB - 1 : col);
            r[8 * h + i] = Wb[(size_t)(rbase + row) * NB + col];
        }
    }
}

// pre-scale by LOG2E at write time (off the relay wave entirely)
__device__ __forceinline__ void writeWt16(float* __restrict__ wt,
                                          const float (&r)[16], int l) {
#pragma unroll
    for (int i = 0; i < 16; ++i) wt[i * WPITCH + l] = r[i] * LOG2E;
}

__device__ __forceinline__ void readWc16(const float* __restrict__ wt, int l,
                                         float (&wc)[16]) {
    const int wb = (l >> 3) * WPITCH + (l & 7) * 8;
    const f4 a = *(const f4*)(wt + wb);
    const f4 b = *(const f4*)(wt + wb + 4);
    const f4 c2 = *(const f4*)(wt + 8 * WPITCH + wb);
    const f4 d = *(const f4*)(wt + 8 * WPITCH + wb + 4);
    wc[0] = a.x;  wc[1] = a.y;  wc[2] = a.z;  wc[3] = a.w;
    wc[4] = b.x;  wc[5] = b.y;  wc[6] = b.z;  wc[7] = b.w;
    wc[8] = c2.x; wc[9] = c2.y; wc[10] = c2.z; wc[11] = c2.w;
    wc[12] = d.x; wc[13] = d.y; wc[14] = d.z; wc[15] = d.w;
}

// FULL: all lanes in j-range for all 16 steps (k in [4,23])
template<bool FULL>
__device__ __forceinline__ void chunk_body(int k, int w, int l,
        float (&wc)[16], float& val, float& diag, float& m2, SharedT& sh)
{
    const int s0 = 1 + k * C;
    const int slot = k % 3;

    // producer boundary ready? (bare spin) + bnd reads FIRST, so their LDS
    // latency overlaps the drained-poll discovery below.
    if (w > 0 && s0 <= NB) {
        const int need = (s0 + C - 1 < NB) ? s0 + C - 1 : NB;
        volatile int* pr = &sh.progress[w - 1];
        while (*pr < need) { }
        __builtin_amdgcn_sched_barrier(0);
        asm volatile("" ::: "memory");
    }
    float bnd[C];
    if (w > 0) {
#pragma unroll
        for (int c = 0; c < C; ++c) {
            const int s = s0 + c;
            bnd[c] = sh.bound[w - 1][s <= NB ? s : NB];
        }
    }

    // stage ring slot free? (3-deep: slot reused every 3 chunks -> 2-period slack)
    if (k >= 3) {
        volatile int* dr = &sh.drained[w][slot];
        while (*dr < k - 3) __builtin_amdgcn_s_sleep(1);
        __builtin_amdgcn_sched_barrier(0);
        asm volatile("" ::: "memory");
    }

    float nvreg[C] = {};
    __builtin_amdgcn_s_setprio(1);
    // ---- 16 relay steps: pure chain only ----
#pragma unroll
    for (int c = 0; c < C; ++c) {
        const int s = s0 + c;
        float upv = __int_as_float(__builtin_amdgcn_update_dpp(
            0, __float_as_int(val), 0x138 /*WAVE_SHR1*/, 0xF, 0xF, false));
        if (l == 0) upv = (w > 0 && s <= NB) ? bnd[c] : NEGV;
        const int j = s - l;
        if (FULL || (j >= 1 && j <= NB)) {
            const float m  = fmaxf(upv, m2);
            const float mw = m + wc[c];              // parallel with exp2s
            const float eu = exp2f(upv  - m);
            const float el = exp2f(val  - m);
            const float ed = exp2f(diag - m);
            const float nv = mw + __log2f((eu + el) + ed);
            nvreg[c] = nv;
            m2   = fmaxf(nv, upv);                   // next step's fmax(val,diag)
            diag = upv;
            val  = nv;
        }
    }

    // ---- RELAY EDGE FIRST: bound writes + progress, at prio 1 ----
    if (w < NCW - 1) {
        if (l == 63) {
#pragma unroll
            for (int c = 0; c < C; ++c) {
                const int j63 = s0 + c - 63;
                if (j63 >= 1 && j63 <= NB) sh.bound[w][j63] = nvreg[c];
            }
        }
        asm volatile("s_waitcnt lgkmcnt(0)" ::: "memory");   // bound only
        if (l == 63) {
            const int done = s0 + C - 1 - 63;                // 16k - 47
            if (done >= 1) *(volatile int*)&sh.progress[w] = done;
        }
    }
    __builtin_amdgcn_s_setprio(0);

    // ---- staging writes + computed publish (off the relay cycle) ----
    float* st = &sh.stage[slot][w][0] + l * SP;
#pragma unroll
    for (int c = 0; c < C; ++c) st[c] = nvreg[c];
    asm volatile("s_waitcnt lgkmcnt(0)" ::: "memory");
    if (l == 63) *(volatile int*)&sh.computed[w] = k + 1;

    // next chunk's W fragment (wready published 2 io-iterations ago -> instant)
    if (k + 1 < TOT_CH) {
        volatile int* wr = &sh.wready[w];
        while (*wr < k + 2) { }
        __builtin_amdgcn_sched_barrier(0);
        asm volatile("" ::: "memory");
        readWc16(&sh.wtile[(k + 1) % 3][w][0], l, wc);
    }
}

// ---------------- IO iteration: drain mu, feed W ----------------
template<bool FULL>
__device__ __forceinline__ void io_iter(int k, int cw, int l,
        const float* __restrict__ Wb, int rbase, float* __restrict__ mub,
        float (&wreg)[16], SharedT& sh)
{
    volatile int* cp = &sh.computed[cw];
    while (*cp < k + 1) __builtin_amdgcn_s_sleep(8);
    __builtin_amdgcn_sched_barrier(0);
    asm volatile("" ::: "memory");

    // stage -> regs (transposed: 4 rows x 16 steps/thread), release slot
    const int slot = k % 3;
    const float* st = &sh.stage[slot][cw][0];
    const int lr = l >> 4, cc = l & 15;            // lr 0..3, cc 0..15
    float v[16];
#pragma unroll
    for (int q = 0; q < 16; ++q) v[q] = st[(lr + 4 * q) * SP + cc];
    asm volatile("s_waitcnt lgkmcnt(0)" ::: "memory");
    if (l == 0) *(volatile int*)&sh.drained[cw][slot] = k;

    // W tile for chunk k+3 from a ~2-period-old register load (vmcnt covered)
    if (k + 3 < TOT_CH) {
        writeWt16(&sh.wtile[(k + 3) % 3][cw][0], wreg, l);
        asm volatile("s_waitcnt lgkmcnt(0)" ::: "memory");
        if (l == 0) *(volatile int*)&sh.wready[cw] = k + 4;
        if (k + 5 < TOT_CH) loadW16(Wb, rbase, k + 5, l, wreg);
    }

    // mu stores LAST (fire-and-forget); 4 rows x 16 consecutive cols / instr
    const int colbase = k * C;
#pragma unroll
    for (int q = 0; q < 16; ++q) {
        const int row = lr + 4 * q;
        const int col = colbase + cc - row;
        if (FULL || (unsigned)col < (unsigned)NB)
            mub[(size_t)(rbase + row + 1) * MUP + col + 1] = v[q] * LN2;
    }
}

__global__ __launch_bounds__(768, 1) void dtw_mu(const float* __restrict__ W,
                                                 float* __restrict__ mu)
{
    __shared__ SharedT sh;
    const int b = blockIdx.x, tid = threadIdx.x;
    const int w = tid >> 6, l = tid & 63;
    const float* Wb = W + (size_t)b * NA * NB;
    float* mub = mu + (size_t)b * MUP * MUP;

    if (tid < 384) {
        mub[tid + 1] = NEGV;                          // row 0, cols 1..384
        mub[(size_t)(tid + 1) * MUP] = NEGV;          // col 0, rows 1..384
    }
    if (tid == 0) mub[0] = 0.0f;
    if (tid < NCW - 1) sh.progress[tid] = 0;
    if (tid < NCW) { sh.computed[tid] = 0; sh.wready[tid] = 0; }
    if (tid < 3 * NCW) sh.drained[tid / 3][tid % 3] = -1;
    __syncthreads();

    if (w < NCW) {
        // ---------------- compute (relay) wave ----------------
        const int rbase = w << 6;
        float val  = NEGV;                            // mu'[r][j-1]
        float diag = (rbase + l == 0) ? 0.0f : NEGV;  // mu'[r-1][0]
        float m2   = fmaxf(val, diag);
        float wc[16];
        {
            volatile int* wr = &sh.wready[w];
            while (*wr < 1) { }
            __builtin_amdgcn_sched_barrier(0);
            asm volatile("" ::: "memory");
            readWc16(&sh.wtile[0][w][0], l, wc);
        }
        for (int k = 0; k < 4; ++k)       chunk_body<false>(k, w, l, wc, val, diag, m2, sh);
        for (int k = 4; k < 24; ++k)      chunk_body<true >(k, w, l, wc, val, diag, m2, sh);
        for (int k = 24; k < TOT_CH; ++k) chunk_body<false>(k, w, l, wc, val, diag, m2, sh);
    } else {
        // ---------------- I/O wave: W feed + mu drain ----------------
        const int cw = w - NCW, rbase = cw << 6;
        float r0[16], rA[16], rB[16];
        loadW16(Wb, rbase, 0, l, r0);
        writeWt16(&sh.wtile[0][cw][0], r0, l);
        loadW16(Wb, rbase, 1, l, r0);
        writeWt16(&sh.wtile[1][cw][0], r0, l);
        loadW16(Wb, rbase, 2, l, r0);
        writeWt16(&sh.wtile[2][cw][0], r0, l);
        loadW16(Wb, rbase, 3, l, rA);
        loadW16(Wb, rbase, 4, l, rB);
        asm volatile("s_waitcnt lgkmcnt(0)" ::: "memory");
        if (l == 0) *(volatile int*)&sh.wready[cw] = 3;

        for (int k = 0; k < 4; k += 2) {
            io_iter<false>(k,     cw, l, Wb, rbase, mub, rA, sh);
            io_iter<false>(k + 1, cw, l, Wb, rbase, mub, rB, sh);
        }
        for (int k = 4; k < 24; k += 2) {
            io_iter<true >(k,     cw, l, Wb, rbase, mub, rA, sh);
            io_iter<true >(k + 1, cw, l, Wb, rbase, mub, rB, sh);
        }
        for (int k = 24; k < TOT_CH; k += 2) {
            io_iter<false>(k,     cw, l, Wb, rbase, mub, rA, sh);
            io_iter<false>(k + 1, cw, l, Wb, rbase, mub, rB, sh);
        }
    }
}

// ---------------- pass 2: pi = exp(x + W - mu_ij) * mask ----------------
__global__ __launch_bounds__(256) void dtw_pi(const float* __restrict__ W,
        const float* __restrict__ mask, const float* __restrict__ mu,
        float* __restrict__ pi)
{
    const long long idx = ((long long)blockIdx.x * 256 + threadIdx.x) * 4;
    const int rr = (int)(idx / NB);
    const int jj = (int)(idx - (long long)rr * NB);
    const int b  = rr / NA;
    const int ii = rr - b * NA;
    const float* m0 = mu + (size_t)b * MUP * MUP + (size_t)ii * MUP + jj;
    const float* m1 = m0 + MUP;
    const float d0 = m0[0], d1 = m0[1], d2 = m0[2], d3 = m0[3], d4 = m0[4];
    const float L0 = m1[0], L1 = m1[1], L2 = m1[2], L3 = m1[3], L4 = m1[4];
    const f4 wv = *(const f4*)(W + idx);
    const f4 mk = *(const f4*)(mask + idx);

    const float t0 = wv.x - L1, t1 = wv.y - L2, t2 = wv.z - L3, t3 = wv.w - L4;
    f4 o0, o1, o2;
    o0.x = exp2f((d1 + t0) * LOG2E) * mk.x;
    o0.y = exp2f((L0 + t0) * LOG2E) * mk.x;
    o0.z = exp2f((d0 + t0) * LOG2E) * mk.x;
    o0.w = exp2f((d2 + t1) * LOG2E) * mk.y;
    o1.x = exp2f((L1 + t1) * LOG2E) * mk.y;
    o1.y = exp2f((d1 + t1) * LOG2E) * mk.y;
    o1.z = exp2f((d3 + t2) * LOG2E) * mk.z;
    o1.w = exp2f((L2 + t2) * LOG2E) * mk.z;
    o2.x = exp2f((d2 + t2) * LOG2E) * mk.z;
    o2.y = exp2f((d4 + t3) * LOG2E) * mk.w;
    o2.z = exp2f((L3 + t3) * LOG2E) * mk.w;
    o2.w = exp2f((d3 + t3) * LOG2E) * mk.w;

    f4* po = (f4*)(pi + idx * 3);
    po[0] = o0; po[1] = o1; po[2] = o2;
}

extern "C" void kernel_launch(void* const* d_in, const int* in_sizes, int n_in,
                              void* d_out, int out_size, void* d_ws, size_t ws_size,
                              hipStream_t stream) {
    const float* W    = (const float*)d_in[0];
    const float* mask = (const float*)d_in[1];
    float* mu = (float*)d_out;
    float* pi = mu + (size_t)NBATCH * MUP * MUP;

    hipLaunchKernelGGL(dtw_mu, dim3(NBATCH), dim3(768), 0, stream, W, mu);

    const int cells  = NBATCH * NA * NB;
    const int blocks = cells / (256 * 4);
    hipLaunchKernelGGL(dtw_pi, dim3(blocks), dim3(256), 0, stream,
                       W, mask, mu, pi);
}

// Round 20
// 143.504 us; speedup vs baseline: 2.0790x; 1.0080x over previous
//
#include <hip/hip_runtime.h>

#define NA 384
#define NB 384
#define NBATCH 64
#define NEGV -1e20f
#define C 16           // steps per chunk
#define NCW 6          // compute waves (rows 64w+1..64w+64)
#define TOT_CH 28      // chunks: s0 = 1 + 16k, k = 0..27
#define WPITCH 68      // wtile row pitch (floats) — MUST be >= 64 (lane index)
#define SP 17          // stage row pitch (16 steps + 1 pad)
#define LOG2E 1.44269504088896340736f
#define LN2   0.69314718055994530942f
#define MUP (NB + 1)

typedef float f4 __attribute__((ext_vector_type(4)));

struct alignas(16) SharedT {
    float stage[2][NCW][64 * SP];      // mu' staging ring
    float wtile[3][NCW][16 * WPITCH];  // transposed W ring (pre-scaled LOG2E)
    float bound[NCW - 1][NB + 1];      // boundary rows mu'[64w][1..384]
    int   progress[NCW - 1];
    int   computed[NCW];
    int   drained[NCW][2];
    int   wready[NCW];
};

// Skewed-coalesced W load (8 cache lines/instr), two 8-col groups.
__device__ __forceinline__ void loadW16(const float* __restrict__ Wb, int rbase,
                                        int k, int l, float (&r)[16])
{
    const int rl = l >> 3, cc = l & 7;
#pragma unroll
    for (int h = 0; h < 2; ++h) {
        const int colb = 8 * (2 * k + h) + cc;
#pragma unroll
        for (int i = 0; i < 8; ++i) {
            const int row = 8 * i + rl;
            int col = colb - row;
            col = col < 0 ? 0 : (col > NB - 1 ? NB - 1 : col);
            r[8 * h + i] = Wb[(size_t)(rbase + row) * NB + col];
        }
    }
}

// pre-scale by LOG2E at write time (off the relay wave entirely)
__device__ __forceinline__ void writeWt16(float* __restrict__ wt,
                                          const float (&r)[16], int l) {
#pragma unroll
    for (int i = 0; i < 16; ++i) wt[i * WPITCH + l] = r[i] * LOG2E;
}

__device__ __forceinline__ void readWc16(const float* __restrict__ wt, int l,
                                         float (&wc)[16]) {
    const int wb = (l >> 3) * WPITCH + (l & 7) * 8;
    const f4 a = *(const f4*)(wt + wb);
    const f4 b = *(const f4*)(wt + wb + 4);
    const f4 c2 = *(const f4*)(wt + 8 * WPITCH + wb);
    const f4 d = *(const f4*)(wt + 8 * WPITCH + wb + 4);
    wc[0] = a.x;  wc[1] = a.y;  wc[2] = a.z;  wc[3] = a.w;
    wc[4] = b.x;  wc[5] = b.y;  wc[6] = b.z;  wc[7] = b.w;
    wc[8] = c2.x; wc[9] = c2.y; wc[10] = c2.z; wc[11] = c2.w;
    wc[12] = d.x; wc[13] = d.y; wc[14] = d.z; wc[15] = d.w;
}

// FULL: all lanes in j-range for all 16 steps (k in [4,23])
template<bool FULL>
__device__ __forceinline__ void chunk_body(int k, int w, int l,
        float (&wc)[16], float& val, float& diag, float& m2, SharedT& sh)
{
    const int s0 = 1 + k * C;

    if (k >= 2) {
        volatile int* dr = &sh.drained[w][k & 1];
        while (*dr < k - 2) __builtin_amdgcn_s_sleep(1);
        __builtin_amdgcn_sched_barrier(0);
        asm volatile("" ::: "memory");
    }
    if (w > 0 && s0 <= NB) {
        const int need = (s0 + C - 1 < NB) ? s0 + C - 1 : NB;
        volatile int* pr = &sh.progress[w - 1];
        while (*pr < need) { }
        __builtin_amdgcn_sched_barrier(0);
        asm volatile("" ::: "memory");
    }
    float bnd[C];
    if (w > 0) {
#pragma unroll
        for (int c = 0; c < C; ++c) {
            const int s = s0 + c;
            bnd[c] = sh.bound[w - 1][s <= NB ? s : NB];
        }
    }

    float nvreg[C] = {};
    __builtin_amdgcn_s_setprio(1);
    // ---- 16 relay steps: pure chain only ----
#pragma unroll
    for (int c = 0; c < C; ++c) {
        const int s = s0 + c;
        float upv = __int_as_float(__builtin_amdgcn_update_dpp(
            0, __float_as_int(val), 0x138 /*WAVE_SHR1*/, 0xF, 0xF, false));
        if (l == 0) upv = (w > 0 && s <= NB) ? bnd[c] : NEGV;
        const int j = s - l;
        if (FULL || (j >= 1 && j <= NB)) {
            const float m  = fmaxf(upv, m2);
            const float mw = m + wc[c];              // parallel with exp2s
            const float eu = exp2f(upv  - m);
            const float el = exp2f(val  - m);
            const float ed = exp2f(diag - m);
            const float nv = mw + __log2f((eu + el) + ed);
            nvreg[c] = nv;
            m2   = fmaxf(nv, upv);                   // next step's fmax(val,diag)
            diag = upv;
            val  = nv;
        }
    }

    // ---- RELAY EDGE FIRST: bound writes + progress, at prio 1 ----
    if (w < NCW - 1) {
        if (l == 63) {
#pragma unroll
            for (int c = 0; c < C; ++c) {
                const int j63 = s0 + c - 63;
                if (j63 >= 1 && j63 <= NB) sh.bound[w][j63] = nvreg[c];
            }
        }
        asm volatile("s_waitcnt lgkmcnt(0)" ::: "memory");   // bound only
        if (l == 63) {
            const int done = s0 + C - 1 - 63;                // 16k - 47
            if (done >= 1) *(volatile int*)&sh.progress[w] = done;
        }
    }
    __builtin_amdgcn_s_setprio(0);

    // ---- staging writes + computed publish (off the relay cycle) ----
    float* st = &sh.stage[k & 1][w][0] + l * SP;
#pragma unroll
    for (int c = 0; c < C; ++c) st[c] = nvreg[c];
    asm volatile("s_waitcnt lgkmcnt(0)" ::: "memory");
    if (l == 63) *(volatile int*)&sh.computed[w] = k + 1;

    // next chunk's W fragment (wready published 2 io-iterations ago -> instant)
    if (k + 1 < TOT_CH) {
        volatile int* wr = &sh.wready[w];
        while (*wr < k + 2) { }
        __builtin_amdgcn_sched_barrier(0);
        asm volatile("" ::: "memory");
        readWc16(&sh.wtile[(k + 1) % 3][w][0], l, wc);
    }
}

// ---------------- IO iteration: drain mu, feed W ----------------
template<bool FULL>
__device__ __forceinline__ void io_iter(int k, int cw, int l,
        const float* __restrict__ Wb, int rbase, float* __restrict__ mub,
        float (&wreg)[16], SharedT& sh)
{
    // deep sleep: IO has ~1 full period of slack; stay off the SIMDs while
    // the compute wave runs its dependent chain.
    volatile int* cp = &sh.computed[cw];
    while (*cp < k + 1) __builtin_amdgcn_s_sleep(8);
    __builtin_amdgcn_sched_barrier(0);
    asm volatile("" ::: "memory");

    // stage -> regs (transposed: 4 rows x 16 steps/thread), release slot
    const float* st = &sh.stage[k & 1][cw][0];
    const int lr = l >> 4, cc = l & 15;            // lr 0..3, cc 0..15
    float v[16];
#pragma unroll
    for (int q = 0; q < 16; ++q) v[q] = st[(lr + 4 * q) * SP + cc];
    asm volatile("s_waitcnt lgkmcnt(0)" ::: "memory");
    if (l == 0) *(volatile int*)&sh.drained[cw][k & 1] = k;

    // W tile for chunk k+3 from a ~2-period-old register load (vmcnt covered)
    if (k + 3 < TOT_CH) {
        writeWt16(&sh.wtile[(k + 3) % 3][cw][0], wreg, l);
        asm volatile("s_waitcnt lgkmcnt(0)" ::: "memory");
        if (l == 0) *(volatile int*)&sh.wready[cw] = k + 4;
        if (k + 5 < TOT_CH) loadW16(Wb, rbase, k + 5, l, wreg);
    }

    // mu stores LAST (fire-and-forget); 4 rows x 16 consecutive cols / instr
    const int colbase = k * C;
#pragma unroll
    for (int q = 0; q < 16; ++q) {
        const int row = lr + 4 * q;
        const int col = colbase + cc - row;
        if (FULL || (unsigned)col < (unsigned)NB)
            mub[(size_t)(rbase + row + 1) * MUP + col + 1] = v[q] * LN2;
    }
}

__global__ __launch_bounds__(768, 1) void dtw_mu(const float* __restrict__ W,
                                                 float* __restrict__ mu)
{
    __shared__ SharedT sh;
    const int b = blockIdx.x, tid = threadIdx.x;
    const int w = tid >> 6, l = tid & 63;
    const float* Wb = W + (size_t)b * NA * NB;
    float* mub = mu + (size_t)b * MUP * MUP;

    if (tid < 384) {
        mub[tid + 1] = NEGV;                          // row 0, cols 1..384
        mub[(size_t)(tid + 1) * MUP] = NEGV;          // col 0, rows 1..384
    }
    if (tid == 0) mub[0] = 0.0f;
    if (tid < NCW - 1) sh.progress[tid] = 0;
    if (tid < NCW) { sh.computed[tid] = 0; sh.wready[tid] = 0; }
    if (tid < 2 * NCW) sh.drained[tid >> 1][tid & 1] = -1;
    __syncthreads();

    if (w < NCW) {
        // ---------------- compute (relay) wave ----------------
        const int rbase = w << 6;
        float val  = NEGV;                            // mu'[r][j-1]
        float diag = (rbase + l == 0) ? 0.0f : NEGV;  // mu'[r-1][0]
        float m2   = fmaxf(val, diag);
        float wc[16];
        {
            volatile int* wr = &sh.wready[w];
            while (*wr < 1) { }
            __builtin_amdgcn_sched_barrier(0);
            asm volatile("" ::: "memory");
            readWc16(&sh.wtile[0][w][0], l, wc);
        }
        for (int k = 0; k < 4; ++k)       chunk_body<false>(k, w, l, wc, val, diag, m2, sh);
        for (int k = 4; k < 24; ++k)      chunk_body<true >(k, w, l, wc, val, diag, m2, sh);
        for (int k = 24; k < TOT_CH; ++k) chunk_body<false>(k, w, l, wc, val, diag, m2, sh);
    } else {
        // ---------------- I/O wave: W feed + mu drain ----------------
        const int cw = w - NCW, rbase = cw << 6;
        float r0[16], rA[16], rB[16];
        loadW16(Wb, rbase, 0, l, r0);
        writeWt16(&sh.wtile[0][cw][0], r0, l);
        loadW16(Wb, rbase, 1, l, r0);
        writeWt16(&sh.wtile[1][cw][0], r0, l);
        loadW16(Wb, rbase, 2, l, r0);
        writeWt16(&sh.wtile[2][cw][0], r0, l);
        loadW16(Wb, rbase, 3, l, rA);
        loadW16(Wb, rbase, 4, l, rB);
        asm volatile("s_waitcnt lgkmcnt(0)" ::: "memory");
        if (l == 0) *(volatile int*)&sh.wready[cw] = 3;

        for (int k = 0; k < 4; k += 2) {
            io_iter<false>(k,     cw, l, Wb, rbase, mub, rA, sh);
            io_iter<false>(k + 1, cw, l, Wb, rbase, mub, rB, sh);
        }
        for (int k = 4; k < 24; k += 2) {
            io_iter<true >(k,     cw, l, Wb, rbase, mub, rA, sh);
            io_iter<true >(k + 1, cw, l, Wb, rbase, mub, rB, sh);
        }
        for (int k = 24; k < TOT_CH; k += 2) {
            io_iter<false>(k,     cw, l, Wb, rbase, mub, rA, sh);
            io_iter<false>(k + 1, cw, l, Wb, rbase, mub, rB, sh);
        }
    }
}

// ---------------- pass 2: pi = exp(x + W - mu_ij) * mask ----------------
__global__ __launch_bounds__(256) void dtw_pi(const float* __restrict__ W,
        const float* __restrict__ mask, const float* __restrict__ mu,
        float* __restrict__ pi)
{
    const long long idx = ((long long)blockIdx.x * 256 + threadIdx.x) * 4;
    const int rr = (int)(idx / NB);
    const int jj = (int)(idx - (long long)rr * NB);
    const int b  = rr / NA;
    const int ii = rr - b * NA;
    const float* m0 = mu + (size_t)b * MUP * MUP + (size_t)ii * MUP + jj;
    const float* m1 = m0 + MUP;
    const float d0 = m0[0], d1 = m0[1], d2 = m0[2], d3 = m0[3], d4 = m0[4];
    const float L0 = m1[0], L1 = m1[1], L2 = m1[2], L3 = m1[3], L4 = m1[4];
    const f4 wv = *(const f4*)(W + idx);
    const f4 mk = *(const f4*)(mask + idx);

    const float t0 = wv.x - L1, t1 = wv.y - L2, t2 = wv.z - L3, t3 = wv.w - L4;
    f4 o0, o1, o2;
    o0.x = exp2f((d1 + t0) * LOG2E) * mk.x;
    o0.y = exp2f((L0 + t0) * LOG2E) * mk.x;
    o0.z = exp2f((d0 + t0) * LOG2E) * mk.x;
    o0.w = exp2f((d2 + t1) * LOG2E) * mk.y;
    o1.x = exp2f((L1 + t1) * LOG2E) * mk.y;
    o1.y = exp2f((d1 + t1) * LOG2E) * mk.y;
    o1.z = exp2f((d3 + t2) * LOG2E) * mk.z;
    o1.w = exp2f((L2 + t2) * LOG2E) * mk.z;
    o2.x = exp2f((d2 + t2) * LOG2E) * mk.z;
    o2.y = exp2f((d4 + t3) * LOG2E) * mk.w;
    o2.z = exp2f((L3 + t3) * LOG2E) * mk.w;
    o2.w = exp2f((d3 + t3) * LOG2E) * mk.w;

    f4* po = (f4*)(pi + idx * 3);
    po[0] = o0; po[1] = o1; po[2] = o2;
}

extern "C" void kernel_launch(void* const* d_in, const int* in_sizes, int n_in,
                              void* d_out, int out_size, void* d_ws, size_t ws_size,
                              hipStream_t stream) {
    const float* W    = (const float*)d_in[0];
    const float* mask = (const float*)d_in[1];
    float* mu = (float*)d_out;
    float* pi = mu + (size_t)NBATCH * MUP * MUP;

    hipLaunchKernelGGL(dtw_mu, dim3(NBATCH), dim3(768), 0, stream, W, mu);

    const int cells  = NBATCH * NA * NB;
    const int blocks = cells / (256 * 4);
    hipLaunchKernelGGL(dtw_pi, dim3(blocks), dim3(256), 0, stream,
                       W, mask, mu, pi);
}